// Round 4
// baseline (175.530 us; speedup 1.0000x reference)
//
#include <hip/hip_runtime.h>
#include <math.h>

#define NB 128     // batch
#define NC 64      // channels
#define NT 128     // segment length
#define HIDN 128   // hidden
#define NE 64      // attn embed
#define NHD 4      // heads
#define HD 16      // head dim

// ---------------------------------------------------------------------------
// 1. Analytic signal (Hilbert, reference mask): bit-identical to rounds 1-3.
// ---------------------------------------------------------------------------
__global__ void analytic_kernel(const float* __restrict__ eeg,
                                float* __restrict__ re, float* __restrict__ im) {
    int row = blockIdx.x;            // b*NC + c
    int b = row >> 6, c = row & 63;
    int t = threadIdx.x;             // 0..127
    __shared__ float xs[NT];
    __shared__ double cotv[64];
    xs[t] = eeg[row * NT + t];
    if (t < 64) {
        double d = (double)(2 * t + 1);
        double a = 3.14159265358979323846 * d / 128.0;
        cotv[t] = cos(a) / sin(a);
    }
    __syncthreads();
    double ar = 0.0, ai = 0.0;
    #pragma unroll
    for (int m = 0; m < 64; ++m) {
        int d = 2 * m + 1;
        int s = (t - d) & 127;
        double xv = (double)xs[s];
        ar += xv;
        ai += cotv[m] * xv;
    }
    double rr = (double)xs[t] + ar * (1.0 / 64.0);
    double ii = ai * (1.0 / 64.0);
    re[b * (NT * NC) + t * NC + c] = (float)rr;
    im[b * (NT * NC) + t * NC + c] = (float)ii;
}

// ---------------------------------------------------------------------------
// 2. PLI (+deg row sums). Bit-identical accumulation to rounds 2-3.
// ---------------------------------------------------------------------------
__global__ void pli_kernel(const float* __restrict__ re, const float* __restrict__ im,
                           float* __restrict__ wpli, float* __restrict__ deg) {
    int blk = blockIdx.x;            // 2048
    int b = blk >> 4;
    int i0 = (blk & 15) << 2;
    int tid = threadIdx.x;           // 256
    int di = tid >> 6, j = tid & 63;
    int i = i0 + di;
    __shared__ float sre[64][64];
    __shared__ float sim[64][64];
    const float* reb = re + b * (NT * NC);
    const float* imb = im + b * (NT * NC);
    int acc = 0;
    #pragma unroll
    for (int tc = 0; tc < 2; ++tc) {
        for (int idx = tid; idx < 4096; idx += 256) {
            sre[idx >> 6][idx & 63] = reb[tc * 4096 + idx];
            sim[idx >> 6][idx & 63] = imb[tc * 4096 + idx];
        }
        __syncthreads();
        #pragma unroll 8
        for (int t = 0; t < 64; ++t) {
            float ri = sre[t][i];
            float ii = sim[t][i];
            float rj = sre[t][j];
            float ij = sim[t][j];
            float cross = ii * rj - ri * ij;
            acc += (cross > 0.f) ? 1 : ((cross < 0.f) ? -1 : 0);
        }
        __syncthreads();
    }
    float p = fabsf((float)acc * (1.f / (float)NT));
    if (j == i) p = 0.f;
    wpli[b * (NC * NC) + i * NC + j] = p;
    float s = p;
    #pragma unroll
    for (int off = 32; off > 0; off >>= 1) s += __shfl_down(s, off);
    if (j == 0) deg[b * NC + i] = s;
}

// ---------------------------------------------------------------------------
// 3. GCN support v2 (unchanged from round 3).
// ---------------------------------------------------------------------------
template <int F, bool BN_X>
__global__ void gcn_support_v2(const float* __restrict__ adj,
                               const float* __restrict__ deg,
                               const float* __restrict__ x,
                               const float* __restrict__ mr,
                               const float* __restrict__ g,
                               const float* __restrict__ bb,
                               float* __restrict__ out) {
    int b = blockIdx.x >> 4;
    int i0 = (blockIdx.x & 15) << 2;
    int tid = threadIdx.x;           // 4*F
    int di = tid / F;                // 0..3
    int f = tid % F;
    int i = i0 + di;
    __shared__ float xs[NC][F + 1];
    __shared__ float arow[4][NC];
    __shared__ float dn[NC];
    if (tid < NC) dn[tid] = (float)(1.0 / sqrt((double)deg[b * NC + tid] + 1e-8));
    __syncthreads();
    if (tid < 4 * NC) {
        int r = tid >> 6, j = tid & 63;
        arow[r][j] = adj[b * NC * NC + (i0 + r) * NC + j] * dn[i0 + r] * dn[j];
    }
    for (int idx4 = tid; idx4 < NC * F / 4; idx4 += 4 * F) {
        int idx = idx4 * 4;
        int j = idx / F, ff = idx % F;
        float4 v = *(const float4*)&x[b * NC * F + idx];
        if (BN_X) {
            float m = mr[2 * j], r = mr[2 * j + 1], gg = g[j], bv = bb[j];
            v.x = (v.x - m) * r * gg + bv; v.x = v.x > 0.f ? v.x : 0.f;
            v.y = (v.y - m) * r * gg + bv; v.y = v.y > 0.f ? v.y : 0.f;
            v.z = (v.z - m) * r * gg + bv; v.z = v.z > 0.f ? v.z : 0.f;
            v.w = (v.w - m) * r * gg + bv; v.w = v.w > 0.f ? v.w : 0.f;
        }
        xs[j][ff] = v.x; xs[j][ff + 1] = v.y; xs[j][ff + 2] = v.z; xs[j][ff + 3] = v.w;
    }
    __syncthreads();
    float acc = 0.f;
    #pragma unroll 16
    for (int jj = 0; jj < NC; ++jj)
        acc += arow[di][jj] * xs[jj][f];
    out[b * NC * F + i * F + f] = acc;
}

// ---------------------------------------------------------------------------
// 4. Tiled GEMM (unchanged): C = A @ W^T + bias, 64x64 tiles.
// ---------------------------------------------------------------------------
template <int K, bool BN_A>
__global__ void gemm64_kernel(const float* __restrict__ A,
                              const float* __restrict__ W,
                              const float* __restrict__ bias,
                              const float* __restrict__ mr,
                              const float* __restrict__ g,
                              const float* __restrict__ bb,
                              float* __restrict__ C, int ldc) {
    int m0 = blockIdx.x * 64;
    int n0 = blockIdx.y * 64;
    int tid = threadIdx.x;           // 256
    int tx = tid & 15, ty = tid >> 4;
    int r0 = ty * 4, c0 = tx * 4;
    __shared__ float AsT[64][65];
    __shared__ float WsT[64][65];
    float acc[4][4] = {};
    #pragma unroll
    for (int ck = 0; ck < K / 64; ++ck) {
        for (int idx = tid; idx < 4096; idx += 256) {
            int kk = idx & 63, r = idx >> 6;
            float v = A[(m0 + r) * K + ck * 64 + kk];
            if (BN_A) {
                int c = (m0 + r) & 63;
                v = (v - mr[2 * c]) * mr[2 * c + 1] * g[c] + bb[c];
                v = v > 0.f ? v : 0.f;
            }
            AsT[kk][r] = v;
            WsT[kk][r] = W[(n0 + r) * K + ck * 64 + kk];
        }
        __syncthreads();
        #pragma unroll 8
        for (int kk = 0; kk < 64; ++kk) {
            float a0 = AsT[kk][r0], a1 = AsT[kk][r0 + 1],
                  a2 = AsT[kk][r0 + 2], a3 = AsT[kk][r0 + 3];
            float w0 = WsT[kk][c0], w1 = WsT[kk][c0 + 1],
                  w2 = WsT[kk][c0 + 2], w3 = WsT[kk][c0 + 3];
            acc[0][0] += a0 * w0; acc[0][1] += a0 * w1; acc[0][2] += a0 * w2; acc[0][3] += a0 * w3;
            acc[1][0] += a1 * w0; acc[1][1] += a1 * w1; acc[1][2] += a1 * w2; acc[1][3] += a1 * w3;
            acc[2][0] += a2 * w0; acc[2][1] += a2 * w1; acc[2][2] += a2 * w2; acc[2][3] += a2 * w3;
            acc[3][0] += a3 * w0; acc[3][1] += a3 * w1; acc[3][2] += a3 * w2; acc[3][3] += a3 * w3;
        }
        __syncthreads();
    }
    float b0 = bias[n0 + c0], b1 = bias[n0 + c0 + 1],
          b2 = bias[n0 + c0 + 2], b3 = bias[n0 + c0 + 3];
    #pragma unroll
    for (int ii = 0; ii < 4; ++ii) {
        float4 v = make_float4(acc[ii][0] + b0, acc[ii][1] + b1,
                               acc[ii][2] + b2, acc[ii][3] + b3);
        *(float4*)&C[(m0 + r0 + ii) * ldc + n0 + c0] = v;
    }
}

// ---------------------------------------------------------------------------
// 5. BN stats per channel (unchanged from round 3).
// ---------------------------------------------------------------------------
__global__ void bn_stats_kernel(const float* __restrict__ x, int F,
                                float* __restrict__ mr) {
    int c = blockIdx.x;
    int tid = threadIdx.x;           // 1024
    double s = 0.0, s2 = 0.0;
    int total = NB * F;
    for (int idx = tid; idx < total; idx += 1024) {
        int b = idx / F, f = idx - b * F;
        float v = x[b * NC * F + c * F + f];
        s += (double)v;
        s2 += (double)v * (double)v;
    }
    __shared__ double ls[1024], ls2[1024];
    ls[tid] = s; ls2[tid] = s2;
    __syncthreads();
    for (int off = 512; off > 0; off >>= 1) {
        if (tid < off) { ls[tid] += ls[tid + off]; ls2[tid] += ls2[tid + off]; }
        __syncthreads();
    }
    if (tid == 0) {
        double N = (double)total;
        double m = ls[0] / N;
        double var = ls2[0] / N - m * m;
        mr[2 * c] = (float)m;
        mr[2 * c + 1] = (float)(1.0 / sqrt(var + 1e-5));
    }
}

// ---------------------------------------------------------------------------
// 6. Fused BN2+ReLU -> QKV -> 4-head attention -> mean-pool -> out-proj.
//    v2: all arrays statically indexed (no scratch), qkv in LDS TRANSPOSED
//    [o][n] so attention reads are float4 same-address broadcasts (free) and
//    phase-1 writes are conflict-free (lane n == bank). ao overwrites dead
//    q rows (own-wave rows only -> no extra sync).
// ---------------------------------------------------------------------------
__global__ __launch_bounds__(256, 1) void attn_fused(
        const float* __restrict__ x2, const float* __restrict__ mr,
        const float* __restrict__ g, const float* __restrict__ bb,
        const float* __restrict__ Win, const float* __restrict__ bin,
        const float* __restrict__ Wout, const float* __restrict__ bout,
        float* __restrict__ feat) {
    int b = blockIdx.x;
    int tid = threadIdx.x;
    int n = tid & 63, og = tid >> 6;       // og == wave id (uniform per wave)
    __shared__ float qkv_s[192][64];       // 48 KB, [output][node]
    __shared__ float mo[64];
    // --- load x row n (BN2 + ReLU) into registers ---
    const float* xrow = x2 + b * 4096 + n * 64;
    float xr[64];
    {
        float m = mr[2 * n], r = mr[2 * n + 1], gg = g[n], bv = bb[n];
        #pragma unroll
        for (int q4 = 0; q4 < 16; ++q4) {
            float4 v = ((const float4*)xrow)[q4];
            float a0 = (v.x - m) * r * gg + bv;
            float a1 = (v.y - m) * r * gg + bv;
            float a2 = (v.z - m) * r * gg + bv;
            float a3 = (v.w - m) * r * gg + bv;
            xr[q4 * 4 + 0] = a0 > 0.f ? a0 : 0.f;
            xr[q4 * 4 + 1] = a1 > 0.f ? a1 : 0.f;
            xr[q4 * 4 + 2] = a2 > 0.f ? a2 : 0.f;
            xr[q4 * 4 + 3] = a3 > 0.f ? a3 : 0.f;
        }
    }
    // --- QKV: o = og*48+u; W float4 wave-uniform loads; write transposed ---
    #pragma unroll 4
    for (int u = 0; u < 48; ++u) {
        int o = og * 48 + u;
        float acc = bin[o];
        const float4* wr = (const float4*)(Win + o * 64);
        #pragma unroll
        for (int d4 = 0; d4 < 16; ++d4) {
            float4 w = wr[d4];
            acc += xr[d4 * 4 + 0] * w.x + xr[d4 * 4 + 1] * w.y
                 + xr[d4 * 4 + 2] * w.z + xr[d4 * 4 + 3] * w.w;
        }
        qkv_s[o][n] = acc;
    }
    __syncthreads();
    // --- attention: thread = (head og, query n) ---
    int e0 = og * HD;
    float q[HD];
    #pragma unroll
    for (int d = 0; d < HD; ++d) q[d] = qkv_s[e0 + d][n];
    float sc[NE];
    #pragma unroll
    for (int j = 0; j < NE; ++j) sc[j] = 0.f;
    #pragma unroll
    for (int d = 0; d < HD; ++d) {
        const float4* krow = (const float4*)&qkv_s[64 + e0 + d][0];
        float qd = q[d];
        #pragma unroll
        for (int j4 = 0; j4 < 16; ++j4) {
            float4 kv = krow[j4];            // same-address broadcast
            sc[j4 * 4 + 0] += qd * kv.x;
            sc[j4 * 4 + 1] += qd * kv.y;
            sc[j4 * 4 + 2] += qd * kv.z;
            sc[j4 * 4 + 3] += qd * kv.w;
        }
    }
    float mx = -1e30f;
    #pragma unroll
    for (int j = 0; j < NE; ++j) mx = fmaxf(mx, sc[j] * 0.25f);
    float sum = 0.f;
    #pragma unroll
    for (int j = 0; j < NE; ++j) { sc[j] = expf(sc[j] * 0.25f - mx); sum += sc[j]; }
    float inv = 1.f / sum;
    float o[HD];
    #pragma unroll
    for (int d = 0; d < HD; ++d) {
        const float4* vrow = (const float4*)&qkv_s[128 + e0 + d][0];
        float acc = 0.f;
        #pragma unroll
        for (int j4 = 0; j4 < 16; ++j4) {
            float4 vv = vrow[j4];            // same-address broadcast
            acc += sc[j4 * 4 + 0] * vv.x + sc[j4 * 4 + 1] * vv.y
                 + sc[j4 * 4 + 2] * vv.z + sc[j4 * 4 + 3] * vv.w;
        }
        o[d] = acc * inv;
    }
    // ao overwrites own-wave q rows (only wave og reads/writes rows e0..e0+15)
    #pragma unroll
    for (int d = 0; d < HD; ++d) qkv_s[e0 + d][n] = o[d];
    __syncthreads();
    // --- mean over nodes (row sums of ao[e][n]) + output projection ---
    if (tid < 64) {
        const float4* arow = (const float4*)&qkv_s[tid][0];
        float s = 0.f;
        #pragma unroll
        for (int n4 = 0; n4 < 16; ++n4) {
            float4 v = arow[n4];
            s += v.x + v.y + v.z + v.w;
        }
        mo[tid] = s * (1.f / 64.f);
    }
    __syncthreads();
    if (tid < 64) {
        float acc = bout[tid];
        const float4* wr = (const float4*)(Wout + tid * 64);
        #pragma unroll
        for (int d4 = 0; d4 < 16; ++d4) {
            float4 w = wr[d4];
            acc += mo[d4 * 4 + 0] * w.x + mo[d4 * 4 + 1] * w.y
                 + mo[d4 * 4 + 2] * w.z + mo[d4 * 4 + 3] * w.w;
        }
        feat[b * NE + tid] = acc;
    }
}

// ---------------------------------------------------------------------------
extern "C" void kernel_launch(void* const* d_in, const int* in_sizes, int n_in,
                              void* d_out, int out_size, void* d_ws, size_t ws_size,
                              hipStream_t stream) {
    const float* eeg      = (const float*)d_in[0];
    const float* gcn1_w   = (const float*)d_in[1];
    const float* gcn1_b   = (const float*)d_in[2];
    const float* gcn2_w   = (const float*)d_in[3];
    const float* gcn2_b   = (const float*)d_in[4];
    const float* bn1_g    = (const float*)d_in[5];
    const float* bn1_b    = (const float*)d_in[6];
    const float* bn2_g    = (const float*)d_in[7];
    const float* bn2_b    = (const float*)d_in[8];
    const float* attn_in_w  = (const float*)d_in[9];
    const float* attn_in_b  = (const float*)d_in[10];
    const float* attn_out_w = (const float*)d_in[11];
    const float* attn_out_b = (const float*)d_in[12];

    float* out  = (float*)d_out;
    float* feat = out;               // [B, E]
    float* wpli = out + NB * NE;     // [B, C, C]

    float* ws = (float*)d_ws;
    float* w_re    = ws;             // [1M] -> reused as s2
    float* w_im    = ws + 1048576;   // [1M]
    float* w_s1    = ws + 2097152;   // [1M]
    float* w_x1    = ws + 3145728;   // [1M]
    float* w_x2    = ws + 4194304;   // [512K]
    float* w_deg   = ws + 4718592;
    float* w_stat1 = ws + 4726784;
    float* w_stat2 = ws + 4726912;
    float* w_s2    = w_re;

    // 1. analytic signal
    analytic_kernel<<<NB * NC, NT, 0, stream>>>(eeg, w_re, w_im);
    // 2. PLI (+deg)
    pli_kernel<<<NB * NC / 4, 256, 0, stream>>>(w_re, w_im, wpli, w_deg);
    // 3. GCN1 support
    gcn_support_v2<NT, false><<<NB * NC / 4, 4 * NT, 0, stream>>>(
        wpli, w_deg, eeg, nullptr, nullptr, nullptr, w_s1);
    // 4. GCN1 linear
    gemm64_kernel<NT, false><<<dim3(NB * NC / 64, HIDN / 64), 256, 0, stream>>>(
        w_s1, gcn1_w, gcn1_b, nullptr, nullptr, nullptr, w_x1, HIDN);
    // 5. BN1 stats
    bn_stats_kernel<<<NC, 1024, 0, stream>>>(w_x1, HIDN, w_stat1);
    // 6. GCN2 support (BN1+ReLU fused at stage)
    gcn_support_v2<HIDN, true><<<NB * NC / 4, 4 * HIDN, 0, stream>>>(
        wpli, w_deg, w_x1, w_stat1, bn1_g, bn1_b, w_s2);
    // 7. GCN2 linear
    gemm64_kernel<HIDN, false><<<dim3(NB * NC / 64, NE / 64), 256, 0, stream>>>(
        w_s2, gcn2_w, gcn2_b, nullptr, nullptr, nullptr, w_x2, NE);
    // 8. BN2 stats
    bn_stats_kernel<<<NC, 1024, 0, stream>>>(w_x2, NE, w_stat2);
    // 9. fused BN2 -> QKV -> attention -> pool -> proj
    attn_fused<<<NB, 256, 0, stream>>>(w_x2, w_stat2, bn2_g, bn2_b,
                                       attn_in_w, attn_in_b,
                                       attn_out_w, attn_out_b, feat);
}

// Round 5
// 164.949 us; speedup vs baseline: 1.0641x; 1.0641x over previous
//
#include <hip/hip_runtime.h>
#include <math.h>

#define NB 128     // batch
#define NC 64      // channels
#define NT 128     // segment length
#define HIDN 128   // hidden
#define NE 64      // attn embed
#define NHD 4      // heads
#define HD 16      // head dim

// ---------------------------------------------------------------------------
// 1. Analytic signal (Hilbert, reference mask): bit-identical to rounds 1-4.
// ---------------------------------------------------------------------------
__global__ void analytic_kernel(const float* __restrict__ eeg,
                                float* __restrict__ re, float* __restrict__ im) {
    int row = blockIdx.x;            // b*NC + c
    int b = row >> 6, c = row & 63;
    int t = threadIdx.x;             // 0..127
    __shared__ float xs[NT];
    __shared__ double cotv[64];
    xs[t] = eeg[row * NT + t];
    if (t < 64) {
        double d = (double)(2 * t + 1);
        double a = 3.14159265358979323846 * d / 128.0;
        cotv[t] = cos(a) / sin(a);
    }
    __syncthreads();
    double ar = 0.0, ai = 0.0;
    #pragma unroll
    for (int m = 0; m < 64; ++m) {
        int d = 2 * m + 1;
        int s = (t - d) & 127;
        double xv = (double)xs[s];
        ar += xv;
        ai += cotv[m] * xv;
    }
    double rr = (double)xs[t] + ar * (1.0 / 64.0);
    double ii = ai * (1.0 / 64.0);
    re[b * (NT * NC) + t * NC + c] = (float)rr;
    im[b * (NT * NC) + t * NC + c] = (float)ii;
}

// ---------------------------------------------------------------------------
// 2. PLI (+deg row sums). Bit-identical accumulation to rounds 2-4.
// ---------------------------------------------------------------------------
__global__ void pli_kernel(const float* __restrict__ re, const float* __restrict__ im,
                           float* __restrict__ wpli, float* __restrict__ deg) {
    int blk = blockIdx.x;            // 2048
    int b = blk >> 4;
    int i0 = (blk & 15) << 2;
    int tid = threadIdx.x;           // 256
    int di = tid >> 6, j = tid & 63;
    int i = i0 + di;
    __shared__ float sre[64][64];
    __shared__ float sim[64][64];
    const float* reb = re + b * (NT * NC);
    const float* imb = im + b * (NT * NC);
    int acc = 0;
    #pragma unroll
    for (int tc = 0; tc < 2; ++tc) {
        for (int idx = tid; idx < 4096; idx += 256) {
            sre[idx >> 6][idx & 63] = reb[tc * 4096 + idx];
            sim[idx >> 6][idx & 63] = imb[tc * 4096 + idx];
        }
        __syncthreads();
        #pragma unroll 8
        for (int t = 0; t < 64; ++t) {
            float ri = sre[t][i];
            float ii = sim[t][i];
            float rj = sre[t][j];
            float ij = sim[t][j];
            float cross = ii * rj - ri * ij;
            acc += (cross > 0.f) ? 1 : ((cross < 0.f) ? -1 : 0);
        }
        __syncthreads();
    }
    float p = fabsf((float)acc * (1.f / (float)NT));
    if (j == i) p = 0.f;
    wpli[b * (NC * NC) + i * NC + j] = p;
    float s = p;
    #pragma unroll
    for (int off = 32; off > 0; off >>= 1) s += __shfl_down(s, off);
    if (j == 0) deg[b * NC + i] = s;
}

// ---------------------------------------------------------------------------
// 3. GCN support v2 (unchanged from round 3).
// ---------------------------------------------------------------------------
template <int F, bool BN_X>
__global__ void gcn_support_v2(const float* __restrict__ adj,
                               const float* __restrict__ deg,
                               const float* __restrict__ x,
                               const float* __restrict__ mr,
                               const float* __restrict__ g,
                               const float* __restrict__ bb,
                               float* __restrict__ out) {
    int b = blockIdx.x >> 4;
    int i0 = (blockIdx.x & 15) << 2;
    int tid = threadIdx.x;           // 4*F
    int di = tid / F;                // 0..3
    int f = tid % F;
    int i = i0 + di;
    __shared__ float xs[NC][F + 1];
    __shared__ float arow[4][NC];
    __shared__ float dn[NC];
    if (tid < NC) dn[tid] = (float)(1.0 / sqrt((double)deg[b * NC + tid] + 1e-8));
    __syncthreads();
    if (tid < 4 * NC) {
        int r = tid >> 6, j = tid & 63;
        arow[r][j] = adj[b * NC * NC + (i0 + r) * NC + j] * dn[i0 + r] * dn[j];
    }
    for (int idx4 = tid; idx4 < NC * F / 4; idx4 += 4 * F) {
        int idx = idx4 * 4;
        int j = idx / F, ff = idx % F;
        float4 v = *(const float4*)&x[b * NC * F + idx];
        if (BN_X) {
            float m = mr[2 * j], r = mr[2 * j + 1], gg = g[j], bv = bb[j];
            v.x = (v.x - m) * r * gg + bv; v.x = v.x > 0.f ? v.x : 0.f;
            v.y = (v.y - m) * r * gg + bv; v.y = v.y > 0.f ? v.y : 0.f;
            v.z = (v.z - m) * r * gg + bv; v.z = v.z > 0.f ? v.z : 0.f;
            v.w = (v.w - m) * r * gg + bv; v.w = v.w > 0.f ? v.w : 0.f;
        }
        xs[j][ff] = v.x; xs[j][ff + 1] = v.y; xs[j][ff + 2] = v.z; xs[j][ff + 3] = v.w;
    }
    __syncthreads();
    float acc = 0.f;
    #pragma unroll 16
    for (int jj = 0; jj < NC; ++jj)
        acc += arow[di][jj] * xs[jj][f];
    out[b * NC * F + i * F + f] = acc;
}

// ---------------------------------------------------------------------------
// 4. Tiled GEMM (unchanged): C = A @ W^T + bias, 64x64 tiles.
// ---------------------------------------------------------------------------
template <int K, bool BN_A>
__global__ void gemm64_kernel(const float* __restrict__ A,
                              const float* __restrict__ W,
                              const float* __restrict__ bias,
                              const float* __restrict__ mr,
                              const float* __restrict__ g,
                              const float* __restrict__ bb,
                              float* __restrict__ C, int ldc) {
    int m0 = blockIdx.x * 64;
    int n0 = blockIdx.y * 64;
    int tid = threadIdx.x;           // 256
    int tx = tid & 15, ty = tid >> 4;
    int r0 = ty * 4, c0 = tx * 4;
    __shared__ float AsT[64][65];
    __shared__ float WsT[64][65];
    float acc[4][4] = {};
    #pragma unroll
    for (int ck = 0; ck < K / 64; ++ck) {
        for (int idx = tid; idx < 4096; idx += 256) {
            int kk = idx & 63, r = idx >> 6;
            float v = A[(m0 + r) * K + ck * 64 + kk];
            if (BN_A) {
                int c = (m0 + r) & 63;
                v = (v - mr[2 * c]) * mr[2 * c + 1] * g[c] + bb[c];
                v = v > 0.f ? v : 0.f;
            }
            AsT[kk][r] = v;
            WsT[kk][r] = W[(n0 + r) * K + ck * 64 + kk];
        }
        __syncthreads();
        #pragma unroll 8
        for (int kk = 0; kk < 64; ++kk) {
            float a0 = AsT[kk][r0], a1 = AsT[kk][r0 + 1],
                  a2 = AsT[kk][r0 + 2], a3 = AsT[kk][r0 + 3];
            float w0 = WsT[kk][c0], w1 = WsT[kk][c0 + 1],
                  w2 = WsT[kk][c0 + 2], w3 = WsT[kk][c0 + 3];
            acc[0][0] += a0 * w0; acc[0][1] += a0 * w1; acc[0][2] += a0 * w2; acc[0][3] += a0 * w3;
            acc[1][0] += a1 * w0; acc[1][1] += a1 * w1; acc[1][2] += a1 * w2; acc[1][3] += a1 * w3;
            acc[2][0] += a2 * w0; acc[2][1] += a2 * w1; acc[2][2] += a2 * w2; acc[2][3] += a2 * w3;
            acc[3][0] += a3 * w0; acc[3][1] += a3 * w1; acc[3][2] += a3 * w2; acc[3][3] += a3 * w3;
        }
        __syncthreads();
    }
    float b0 = bias[n0 + c0], b1 = bias[n0 + c0 + 1],
          b2 = bias[n0 + c0 + 2], b3 = bias[n0 + c0 + 3];
    #pragma unroll
    for (int ii = 0; ii < 4; ++ii) {
        float4 v = make_float4(acc[ii][0] + b0, acc[ii][1] + b1,
                               acc[ii][2] + b2, acc[ii][3] + b3);
        *(float4*)&C[(m0 + r0 + ii) * ldc + n0 + c0] = v;
    }
}

// ---------------------------------------------------------------------------
// 5. BN stats per channel (unchanged).
// ---------------------------------------------------------------------------
__global__ void bn_stats_kernel(const float* __restrict__ x, int F,
                                float* __restrict__ mr) {
    int c = blockIdx.x;
    int tid = threadIdx.x;           // 1024
    double s = 0.0, s2 = 0.0;
    int total = NB * F;
    for (int idx = tid; idx < total; idx += 1024) {
        int b = idx / F, f = idx - b * F;
        float v = x[b * NC * F + c * F + f];
        s += (double)v;
        s2 += (double)v * (double)v;
    }
    __shared__ double ls[1024], ls2[1024];
    ls[tid] = s; ls2[tid] = s2;
    __syncthreads();
    for (int off = 512; off > 0; off >>= 1) {
        if (tid < off) { ls[tid] += ls[tid + off]; ls2[tid] += ls2[tid + off]; }
        __syncthreads();
    }
    if (tid == 0) {
        double N = (double)total;
        double m = ls[0] / N;
        double var = ls2[0] / N - m * m;
        mr[2 * c] = (float)m;
        mr[2 * c + 1] = (float)(1.0 / sqrt(var + 1e-5));
    }
}

// ---------------------------------------------------------------------------
// 6. Fused BN2+ReLU -> QKV -> attention -> pool -> proj.  v3: 1024 threads
//    (16 waves -> 4 waves/SIMD of TLP). QKV: wave w computes output rows
//    o = w + 16r (wave-uniform W reads). Attention: 4-way j-split per (h,n);
//    softmax combined via LDS partials; PV partials accumulated into the dead
//    q-region over 4 deterministic rounds; 1/sum applied in the last round.
// ---------------------------------------------------------------------------
__global__ __launch_bounds__(1024, 1) void attn_fused(
        const float* __restrict__ x2, const float* __restrict__ mr,
        const float* __restrict__ g, const float* __restrict__ bb,
        const float* __restrict__ Win, const float* __restrict__ bin,
        const float* __restrict__ Wout, const float* __restrict__ bout,
        float* __restrict__ feat) {
    int b = blockIdx.x;
    int tid = threadIdx.x;           // 0..1023
    int n = tid & 63;
    int ow = tid >> 6;               // wave id 0..15
    __shared__ float qkv_s[192][64]; // 48 KB, [output][node]
    __shared__ float pm_s[4][256];   // partial max  [jc][h*64+n]
    __shared__ float ps_s[4][256];   // partial sum
    __shared__ float pool_s[64][17];
    __shared__ float mo[64];

    // --- x row n (BN2 + ReLU) into registers ---
    const float* xrow = x2 + b * 4096 + n * 64;
    float xr[64];
    {
        float m = mr[2 * n], r = mr[2 * n + 1], gg = g[n], bv = bb[n];
        #pragma unroll
        for (int q4 = 0; q4 < 16; ++q4) {
            float4 v = ((const float4*)xrow)[q4];
            float a0 = (v.x - m) * r * gg + bv;
            float a1 = (v.y - m) * r * gg + bv;
            float a2 = (v.z - m) * r * gg + bv;
            float a3 = (v.w - m) * r * gg + bv;
            xr[q4 * 4 + 0] = a0 > 0.f ? a0 : 0.f;
            xr[q4 * 4 + 1] = a1 > 0.f ? a1 : 0.f;
            xr[q4 * 4 + 2] = a2 > 0.f ? a2 : 0.f;
            xr[q4 * 4 + 3] = a3 > 0.f ? a3 : 0.f;
        }
    }
    // --- QKV: 12 output rows per wave, o = ow + 16r (wave-uniform) ---
    #pragma unroll
    for (int r = 0; r < 12; ++r) {
        int o = ow + r * 16;
        float acc = bin[o];
        const float4* wr = (const float4*)(Win + o * 64);
        #pragma unroll
        for (int d4 = 0; d4 < 16; ++d4) {
            float4 w = wr[d4];
            acc += xr[d4 * 4 + 0] * w.x + xr[d4 * 4 + 1] * w.y
                 + xr[d4 * 4 + 2] * w.z + xr[d4 * 4 + 3] * w.w;
        }
        qkv_s[o][n] = acc;           // bank = n&31, 2-way (free)
    }
    __syncthreads();

    // --- attention: thread = (jc = ow>>2, h = ow&3, n) ---
    int h = ow & 3, jc = ow >> 2;
    int e0 = h * HD, j0 = jc * 16, hn = h * 64 + n;
    float q[HD];
    #pragma unroll
    for (int d = 0; d < HD; ++d) q[d] = qkv_s[e0 + d][n];
    float sc[16];
    #pragma unroll
    for (int jj = 0; jj < 16; ++jj) sc[jj] = 0.f;
    #pragma unroll
    for (int d = 0; d < HD; ++d) {
        const float4* krow = (const float4*)&qkv_s[64 + e0 + d][j0]; // wave-uniform
        float qd = q[d];
        #pragma unroll
        for (int j4 = 0; j4 < 4; ++j4) {
            float4 kv = krow[j4];
            sc[j4 * 4 + 0] += qd * kv.x;
            sc[j4 * 4 + 1] += qd * kv.y;
            sc[j4 * 4 + 2] += qd * kv.z;
            sc[j4 * 4 + 3] += qd * kv.w;
        }
    }
    float pmax = -1e30f;
    #pragma unroll
    for (int jj = 0; jj < 16; ++jj) { sc[jj] *= 0.25f; pmax = fmaxf(pmax, sc[jj]); }
    pm_s[jc][hn] = pmax;
    __syncthreads();
    float mx = fmaxf(fmaxf(pm_s[0][hn], pm_s[1][hn]),
                     fmaxf(pm_s[2][hn], pm_s[3][hn]));
    float psum = 0.f;
    #pragma unroll
    for (int jj = 0; jj < 16; ++jj) { sc[jj] = expf(sc[jj] - mx); psum += sc[jj]; }
    ps_s[jc][hn] = psum;
    // --- PV partials over this thread's 16 keys ---
    float po[HD];
    #pragma unroll
    for (int d = 0; d < HD; ++d) {
        const float4* vrow = (const float4*)&qkv_s[128 + e0 + d][j0]; // wave-uniform
        float acc = 0.f;
        #pragma unroll
        for (int j4 = 0; j4 < 4; ++j4) {
            float4 vv = vrow[j4];
            acc += sc[j4 * 4 + 0] * vv.x + sc[j4 * 4 + 1] * vv.y
                 + sc[j4 * 4 + 2] * vv.z + sc[j4 * 4 + 3] * vv.w;
        }
        po[d] = acc;
    }
    __syncthreads();
    float inv = 1.f / (ps_s[0][hn] + ps_s[1][hn] + ps_s[2][hn] + ps_s[3][hn]);
    // --- combine PV partials into dead q-region (4 deterministic rounds) ---
    if (jc == 0) {
        #pragma unroll
        for (int d = 0; d < HD; ++d) qkv_s[e0 + d][n] = po[d];
    }
    __syncthreads();
    if (jc == 1) {
        #pragma unroll
        for (int d = 0; d < HD; ++d) qkv_s[e0 + d][n] += po[d];
    }
    __syncthreads();
    if (jc == 2) {
        #pragma unroll
        for (int d = 0; d < HD; ++d) qkv_s[e0 + d][n] += po[d];
    }
    __syncthreads();
    if (jc == 3) {
        #pragma unroll
        for (int d = 0; d < HD; ++d)
            qkv_s[e0 + d][n] = (qkv_s[e0 + d][n] + po[d]) * inv;
    }
    __syncthreads();
    // --- mean over nodes: 16 partial sums per output dim ---
    {
        int e = tid >> 4, part = tid & 15;
        float4 v = *(const float4*)&qkv_s[e][part * 4];
        pool_s[e][part] = v.x + v.y + v.z + v.w;
    }
    __syncthreads();
    if (tid < 64) {
        float s = 0.f;
        #pragma unroll
        for (int p = 0; p < 16; ++p) s += pool_s[tid][p];
        mo[tid] = s * (1.f / 64.f);
    }
    __syncthreads();
    if (tid < 64) {
        float acc = bout[tid];
        const float4* wr = (const float4*)(Wout + tid * 64);
        #pragma unroll
        for (int d4 = 0; d4 < 16; ++d4) {
            float4 w = wr[d4];
            acc += mo[d4 * 4 + 0] * w.x + mo[d4 * 4 + 1] * w.y
                 + mo[d4 * 4 + 2] * w.z + mo[d4 * 4 + 3] * w.w;
        }
        feat[b * NE + tid] = acc;
    }
}

// ---------------------------------------------------------------------------
extern "C" void kernel_launch(void* const* d_in, const int* in_sizes, int n_in,
                              void* d_out, int out_size, void* d_ws, size_t ws_size,
                              hipStream_t stream) {
    const float* eeg      = (const float*)d_in[0];
    const float* gcn1_w   = (const float*)d_in[1];
    const float* gcn1_b   = (const float*)d_in[2];
    const float* gcn2_w   = (const float*)d_in[3];
    const float* gcn2_b   = (const float*)d_in[4];
    const float* bn1_g    = (const float*)d_in[5];
    const float* bn1_b    = (const float*)d_in[6];
    const float* bn2_g    = (const float*)d_in[7];
    const float* bn2_b    = (const float*)d_in[8];
    const float* attn_in_w  = (const float*)d_in[9];
    const float* attn_in_b  = (const float*)d_in[10];
    const float* attn_out_w = (const float*)d_in[11];
    const float* attn_out_b = (const float*)d_in[12];

    float* out  = (float*)d_out;
    float* feat = out;               // [B, E]
    float* wpli = out + NB * NE;     // [B, C, C]

    float* ws = (float*)d_ws;
    float* w_re    = ws;             // [1M] -> reused as s2
    float* w_im    = ws + 1048576;   // [1M]
    float* w_s1    = ws + 2097152;   // [1M]
    float* w_x1    = ws + 3145728;   // [1M]
    float* w_x2    = ws + 4194304;   // [512K]
    float* w_deg   = ws + 4718592;
    float* w_stat1 = ws + 4726784;
    float* w_stat2 = ws + 4726912;
    float* w_s2    = w_re;

    // 1. analytic signal
    analytic_kernel<<<NB * NC, NT, 0, stream>>>(eeg, w_re, w_im);
    // 2. PLI (+deg)
    pli_kernel<<<NB * NC / 4, 256, 0, stream>>>(w_re, w_im, wpli, w_deg);
    // 3. GCN1 support
    gcn_support_v2<NT, false><<<NB * NC / 4, 4 * NT, 0, stream>>>(
        wpli, w_deg, eeg, nullptr, nullptr, nullptr, w_s1);
    // 4. GCN1 linear
    gemm64_kernel<NT, false><<<dim3(NB * NC / 64, HIDN / 64), 256, 0, stream>>>(
        w_s1, gcn1_w, gcn1_b, nullptr, nullptr, nullptr, w_x1, HIDN);
    // 5. BN1 stats
    bn_stats_kernel<<<NC, 1024, 0, stream>>>(w_x1, HIDN, w_stat1);
    // 6. GCN2 support (BN1+ReLU fused at stage)
    gcn_support_v2<HIDN, true><<<NB * NC / 4, 4 * HIDN, 0, stream>>>(
        wpli, w_deg, w_x1, w_stat1, bn1_g, bn1_b, w_s2);
    // 7. GCN2 linear
    gemm64_kernel<HIDN, false><<<dim3(NB * NC / 64, NE / 64), 256, 0, stream>>>(
        w_s2, gcn2_w, gcn2_b, nullptr, nullptr, nullptr, w_x2, NE);
    // 8. BN2 stats
    bn_stats_kernel<<<NC, 1024, 0, stream>>>(w_x2, NE, w_stat2);
    // 9. fused BN2 -> QKV -> attention -> pool -> proj (1024 threads)
    attn_fused<<<NB, 1024, 0, stream>>>(w_x2, w_stat2, bn2_g, bn2_b,
                                        attn_in_w, attn_in_b,
                                        attn_out_w, attn_out_b, feat);
}

// Round 6
// 141.231 us; speedup vs baseline: 1.2429x; 1.1679x over previous
//
#include <hip/hip_runtime.h>
#include <math.h>

#define NB 128     // batch
#define NC 64      // channels
#define NT 128     // segment length
#define HIDN 128   // hidden
#define NE 64      // attn embed
#define NHD 4      // heads
#define HD 16      // head dim

// ---------------------------------------------------------------------------
// 1. Analytic signal. Math bit-identical to rounds 1-5; output layout now
//    [b][c][t] (coalesced stores along t; pli v3 stages [c][t] rows).
// ---------------------------------------------------------------------------
__global__ void analytic_kernel(const float* __restrict__ eeg,
                                float* __restrict__ re, float* __restrict__ im) {
    int row = blockIdx.x;            // b*NC + c
    int t = threadIdx.x;             // 0..127
    __shared__ float xs[NT];
    __shared__ double cotv[64];
    xs[t] = eeg[row * NT + t];
    if (t < 64) {
        double d = (double)(2 * t + 1);
        double a = 3.14159265358979323846 * d / 128.0;
        cotv[t] = cos(a) / sin(a);
    }
    __syncthreads();
    double ar = 0.0, ai = 0.0;
    #pragma unroll
    for (int m = 0; m < 64; ++m) {
        int d = 2 * m + 1;
        int s = (t - d) & 127;
        double xv = (double)xs[s];
        ar += xv;
        ai += cotv[m] * xv;
    }
    double rr = (double)xs[t] + ar * (1.0 / 64.0);
    double ii = ai * (1.0 / 64.0);
    re[row * NT + t] = (float)rr;    // [b][c][t], coalesced
    im[row * NT + t] = (float)ii;
}

// ---------------------------------------------------------------------------
// 2. PLI v3. Full per-batch slice staged as XOR-swizzled float4 (even bank
//    spread for row-reads); t vectorized x4; waves split the t-range so each
//    (j-row) float4 is read ONCE per 4 i-values (4x LDS traffic cut). Integer
//    partial sums combined exactly (order-independent) -> bit-identical PLI.
// ---------------------------------------------------------------------------
__global__ void pli_kernel(const float* __restrict__ re, const float* __restrict__ im,
                           float* __restrict__ wpli, float* __restrict__ deg) {
    int b = blockIdx.x >> 4;
    int i0 = (blockIdx.x & 15) << 2;
    int tid = threadIdx.x;           // 256
    int w = tid >> 6;                // wave -> t-chunk
    int j = tid & 63;
    __shared__ float4 sre4[64 * 32]; // 32 KB, slot = c*32 + (t4 ^ (c&31))
    __shared__ float4 sim4[64 * 32]; // 32 KB
    __shared__ int pacc[4][4][64];   // [t-chunk][di][j]
    const float* reb = re + b * (NC * NT);   // [c][t]
    const float* imb = im + b * (NC * NT);
    for (int idx4 = tid; idx4 < 2048; idx4 += 256) {
        int c = idx4 >> 5, t4 = idx4 & 31;
        int slot = c * 32 + (t4 ^ (c & 31));
        sre4[slot] = ((const float4*)reb)[idx4];
        sim4[slot] = ((const float4*)imb)[idx4];
    }
    __syncthreads();
    int acc0 = 0, acc1 = 0, acc2 = 0, acc3 = 0;
    #pragma unroll
    for (int tt = 0; tt < 8; ++tt) {
        int t4 = w * 8 + tt;
        float4 rj = sre4[j * 32 + (t4 ^ (j & 31))];
        float4 ij = sim4[j * 32 + (t4 ^ (j & 31))];
        #pragma unroll
        for (int di = 0; di < 4; ++di) {
            int i = i0 + di;
            float4 ri = sre4[i * 32 + (t4 ^ (i & 31))];  // wave-uniform
            float4 ii = sim4[i * 32 + (t4 ^ (i & 31))];
            float c0 = ii.x * rj.x - ri.x * ij.x;
            float c1 = ii.y * rj.y - ri.y * ij.y;
            float c2 = ii.z * rj.z - ri.z * ij.z;
            float c3 = ii.w * rj.w - ri.w * ij.w;
            int d = ((c0 > 0.f) ? 1 : ((c0 < 0.f) ? -1 : 0))
                  + ((c1 > 0.f) ? 1 : ((c1 < 0.f) ? -1 : 0))
                  + ((c2 > 0.f) ? 1 : ((c2 < 0.f) ? -1 : 0))
                  + ((c3 > 0.f) ? 1 : ((c3 < 0.f) ? -1 : 0));
            if (di == 0) acc0 += d;
            else if (di == 1) acc1 += d;
            else if (di == 2) acc2 += d;
            else acc3 += d;
        }
    }
    pacc[w][0][j] = acc0; pacc[w][1][j] = acc1;
    pacc[w][2][j] = acc2; pacc[w][3][j] = acc3;
    __syncthreads();
    int di2 = tid >> 6, j2 = tid & 63;
    int a = pacc[0][di2][j2] + pacc[1][di2][j2] + pacc[2][di2][j2] + pacc[3][di2][j2];
    float p = fabsf((float)a * (1.f / (float)NT));
    int i = i0 + di2;
    if (j2 == i) p = 0.f;
    wpli[b * (NC * NC) + i * NC + j2] = p;
    float s = p;
    #pragma unroll
    for (int off = 32; off > 0; off >>= 1) s += __shfl_down(s, off);
    if (j2 == 0) deg[b * NC + i] = s;
}

// ---------------------------------------------------------------------------
// 3. GCN support v2 (unchanged from round 3).
// ---------------------------------------------------------------------------
template <int F, bool BN_X>
__global__ void gcn_support_v2(const float* __restrict__ adj,
                               const float* __restrict__ deg,
                               const float* __restrict__ x,
                               const float* __restrict__ mr,
                               const float* __restrict__ g,
                               const float* __restrict__ bb,
                               float* __restrict__ out) {
    int b = blockIdx.x >> 4;
    int i0 = (blockIdx.x & 15) << 2;
    int tid = threadIdx.x;           // 4*F
    int di = tid / F;                // 0..3
    int f = tid % F;
    int i = i0 + di;
    __shared__ float xs[NC][F + 1];
    __shared__ float arow[4][NC];
    __shared__ float dn[NC];
    if (tid < NC) dn[tid] = (float)(1.0 / sqrt((double)deg[b * NC + tid] + 1e-8));
    __syncthreads();
    if (tid < 4 * NC) {
        int r = tid >> 6, jj = tid & 63;
        arow[r][jj] = adj[b * NC * NC + (i0 + r) * NC + jj] * dn[i0 + r] * dn[jj];
    }
    for (int idx4 = tid; idx4 < NC * F / 4; idx4 += 4 * F) {
        int idx = idx4 * 4;
        int jj = idx / F, ff = idx % F;
        float4 v = *(const float4*)&x[b * NC * F + idx];
        if (BN_X) {
            float m = mr[2 * jj], r = mr[2 * jj + 1], gg = g[jj], bv = bb[jj];
            v.x = (v.x - m) * r * gg + bv; v.x = v.x > 0.f ? v.x : 0.f;
            v.y = (v.y - m) * r * gg + bv; v.y = v.y > 0.f ? v.y : 0.f;
            v.z = (v.z - m) * r * gg + bv; v.z = v.z > 0.f ? v.z : 0.f;
            v.w = (v.w - m) * r * gg + bv; v.w = v.w > 0.f ? v.w : 0.f;
        }
        xs[jj][ff] = v.x; xs[jj][ff + 1] = v.y; xs[jj][ff + 2] = v.z; xs[jj][ff + 3] = v.w;
    }
    __syncthreads();
    float acc = 0.f;
    #pragma unroll 16
    for (int jj = 0; jj < NC; ++jj)
        acc += arow[di][jj] * xs[jj][f];
    out[b * NC * F + i * F + f] = acc;
}

// ---------------------------------------------------------------------------
// 4. Tiled GEMM (unchanged): C = A @ W^T + bias, 64x64 tiles.
// ---------------------------------------------------------------------------
template <int K, bool BN_A>
__global__ void gemm64_kernel(const float* __restrict__ A,
                              const float* __restrict__ W,
                              const float* __restrict__ bias,
                              const float* __restrict__ mr,
                              const float* __restrict__ g,
                              const float* __restrict__ bb,
                              float* __restrict__ C, int ldc) {
    int m0 = blockIdx.x * 64;
    int n0 = blockIdx.y * 64;
    int tid = threadIdx.x;           // 256
    int tx = tid & 15, ty = tid >> 4;
    int r0 = ty * 4, c0 = tx * 4;
    __shared__ float AsT[64][65];
    __shared__ float WsT[64][65];
    float acc[4][4] = {};
    #pragma unroll
    for (int ck = 0; ck < K / 64; ++ck) {
        for (int idx = tid; idx < 4096; idx += 256) {
            int kk = idx & 63, r = idx >> 6;
            float v = A[(m0 + r) * K + ck * 64 + kk];
            if (BN_A) {
                int c = (m0 + r) & 63;
                v = (v - mr[2 * c]) * mr[2 * c + 1] * g[c] + bb[c];
                v = v > 0.f ? v : 0.f;
            }
            AsT[kk][r] = v;
            WsT[kk][r] = W[(n0 + r) * K + ck * 64 + kk];
        }
        __syncthreads();
        #pragma unroll 8
        for (int kk = 0; kk < 64; ++kk) {
            float a0 = AsT[kk][r0], a1 = AsT[kk][r0 + 1],
                  a2 = AsT[kk][r0 + 2], a3 = AsT[kk][r0 + 3];
            float w0 = WsT[kk][c0], w1 = WsT[kk][c0 + 1],
                  w2 = WsT[kk][c0 + 2], w3 = WsT[kk][c0 + 3];
            acc[0][0] += a0 * w0; acc[0][1] += a0 * w1; acc[0][2] += a0 * w2; acc[0][3] += a0 * w3;
            acc[1][0] += a1 * w0; acc[1][1] += a1 * w1; acc[1][2] += a1 * w2; acc[1][3] += a1 * w3;
            acc[2][0] += a2 * w0; acc[2][1] += a2 * w1; acc[2][2] += a2 * w2; acc[2][3] += a2 * w3;
            acc[3][0] += a3 * w0; acc[3][1] += a3 * w1; acc[3][2] += a3 * w2; acc[3][3] += a3 * w3;
        }
        __syncthreads();
    }
    float b0 = bias[n0 + c0], b1 = bias[n0 + c0 + 1],
          b2 = bias[n0 + c0 + 2], b3 = bias[n0 + c0 + 3];
    #pragma unroll
    for (int ii = 0; ii < 4; ++ii) {
        float4 v = make_float4(acc[ii][0] + b0, acc[ii][1] + b1,
                               acc[ii][2] + b2, acc[ii][3] + b3);
        *(float4*)&C[(m0 + r0 + ii) * ldc + n0 + c0] = v;
    }
}

// ---------------------------------------------------------------------------
// 5. BN stats per channel (unchanged).
// ---------------------------------------------------------------------------
__global__ void bn_stats_kernel(const float* __restrict__ x, int F,
                                float* __restrict__ mr) {
    int c = blockIdx.x;
    int tid = threadIdx.x;           // 1024
    double s = 0.0, s2 = 0.0;
    int total = NB * F;
    for (int idx = tid; idx < total; idx += 1024) {
        int b = idx / F, f = idx - b * F;
        float v = x[b * NC * F + c * F + f];
        s += (double)v;
        s2 += (double)v * (double)v;
    }
    __shared__ double ls[1024], ls2[1024];
    ls[tid] = s; ls2[tid] = s2;
    __syncthreads();
    for (int off = 512; off > 0; off >>= 1) {
        if (tid < off) { ls[tid] += ls[tid + off]; ls2[tid] += ls2[tid + off]; }
        __syncthreads();
    }
    if (tid == 0) {
        double N = (double)total;
        double m = ls[0] / N;
        double var = ls2[0] / N - m * m;
        mr[2 * c] = (float)m;
        mr[2 * c + 1] = (float)(1.0 / sqrt(var + 1e-5));
    }
}

// ---------------------------------------------------------------------------
// 6. Attention v4: one block per (b, head), 256 threads (4 waves).
//    BN2+ReLU'd x and the head's 48 W-rows staged in LDS; QKV via per-thread
//    12-accumulator register tile (x read once per d4, W wave-uniform
//    broadcast); scores/PV with j-split 4 ways (wave = j-chunk, K/V reads
//    fully wave-uniform); exact-order partial combines; writes pooled
//    means to w_mo[b][h*16+d].
// ---------------------------------------------------------------------------
__global__ __launch_bounds__(256) void attn_fused(
        const float* __restrict__ x2, const float* __restrict__ mr,
        const float* __restrict__ g, const float* __restrict__ bb,
        const float* __restrict__ Win, const float* __restrict__ bin,
        float* __restrict__ w_mo) {
    int b = blockIdx.x >> 2, h = blockIdx.x & 3;
    int tid = threadIdx.x;
    int lane = tid & 63, wv = tid >> 6;   // wv: wave id 0..3 (uniform)
    __shared__ float xs[64][65];          // BN'd x, [n][d]
    __shared__ float ws[48][64];          // W rows: q(0..15) k(16..31) v(32..47)
    __shared__ float kqkv[48][64];        // [dim][n]: q/k/v, q later = ao
    __shared__ float pv_s[4][16][64];     // PV partials [jchunk][d][n]
    __shared__ float pm_s[4][64], ps_s[4][64];
    __shared__ float pool2[16][17];
    const float* xb = x2 + b * 4096;

    // stage x (BN2+ReLU applied)
    for (int idx4 = tid; idx4 < 1024; idx4 += 256) {
        int r = idx4 >> 4, c4 = idx4 & 15;
        float4 v = ((const float4*)xb)[idx4];
        float m = mr[2 * r], rs = mr[2 * r + 1], gg = g[r], bv = bb[r];
        v.x = (v.x - m) * rs * gg + bv; v.x = v.x > 0.f ? v.x : 0.f;
        v.y = (v.y - m) * rs * gg + bv; v.y = v.y > 0.f ? v.y : 0.f;
        v.z = (v.z - m) * rs * gg + bv; v.z = v.z > 0.f ? v.z : 0.f;
        v.w = (v.w - m) * rs * gg + bv; v.w = v.w > 0.f ? v.w : 0.f;
        *(float4*)&xs[r][c4 * 4] = v;
    }
    // stage this head's 48 W rows
    for (int idx4 = tid; idx4 < 768; idx4 += 256) {
        int rl = idx4 >> 4, c4 = idx4 & 15;
        int rg = ((rl >> 4) << 6) + (h << 4) + (rl & 15);
        *(float4*)&ws[rl][c4 * 4] = ((const float4*)(Win + rg * 64))[c4];
    }
    __syncthreads();

    // --- QKV: thread (lane=n, wv); 12 outputs o_local = wv + 4u ---
    float acc[12];
    #pragma unroll
    for (int u = 0; u < 12; ++u) {
        int ol = wv + 4 * u;
        acc[u] = bin[((ol >> 4) << 6) + (h << 4) + (ol & 15)];
    }
    #pragma unroll
    for (int d4 = 0; d4 < 16; ++d4) {
        float4 xv = *(const float4*)&xs[lane][d4 * 4];
        #pragma unroll
        for (int u = 0; u < 12; ++u) {
            float4 wv4 = *(const float4*)&ws[wv + 4 * u][d4 * 4];  // broadcast
            acc[u] += xv.x * wv4.x + xv.y * wv4.y + xv.z * wv4.z + xv.w * wv4.w;
        }
    }
    #pragma unroll
    for (int u = 0; u < 12; ++u) kqkv[wv + 4 * u][lane] = acc[u];
    __syncthreads();

    // --- scores: thread (n=lane, jq=wv), 16 keys each ---
    int j0 = wv * 16;
    float sc[16];
    #pragma unroll
    for (int jj = 0; jj < 16; ++jj) sc[jj] = 0.f;
    #pragma unroll
    for (int d = 0; d < 16; ++d) {
        float qd = kqkv[d][lane];
        #pragma unroll
        for (int j4 = 0; j4 < 4; ++j4) {
            float4 kv4 = *(const float4*)&kqkv[16 + d][j0 + j4 * 4];  // uniform
            sc[j4 * 4 + 0] += qd * kv4.x;
            sc[j4 * 4 + 1] += qd * kv4.y;
            sc[j4 * 4 + 2] += qd * kv4.z;
            sc[j4 * 4 + 3] += qd * kv4.w;
        }
    }
    float pmax = -1e30f;
    #pragma unroll
    for (int jj = 0; jj < 16; ++jj) { sc[jj] *= 0.25f; pmax = fmaxf(pmax, sc[jj]); }
    pm_s[wv][lane] = pmax;
    __syncthreads();
    float mx = fmaxf(fmaxf(pm_s[0][lane], pm_s[1][lane]),
                     fmaxf(pm_s[2][lane], pm_s[3][lane]));
    float psum = 0.f;
    #pragma unroll
    for (int jj = 0; jj < 16; ++jj) { sc[jj] = expf(sc[jj] - mx); psum += sc[jj]; }
    ps_s[wv][lane] = psum;
    // --- PV partials over this thread's 16 keys ---
    #pragma unroll
    for (int d = 0; d < 16; ++d) {
        float4 v0 = *(const float4*)&kqkv[32 + d][j0 + 0];   // uniform
        float4 v1 = *(const float4*)&kqkv[32 + d][j0 + 4];
        float4 v2 = *(const float4*)&kqkv[32 + d][j0 + 8];
        float4 v3 = *(const float4*)&kqkv[32 + d][j0 + 12];
        float a = sc[0] * v0.x + sc[1] * v0.y + sc[2] * v0.z + sc[3] * v0.w
                + sc[4] * v1.x + sc[5] * v1.y + sc[6] * v1.z + sc[7] * v1.w
                + sc[8] * v2.x + sc[9] * v2.y + sc[10] * v2.z + sc[11] * v2.w
                + sc[12] * v3.x + sc[13] * v3.y + sc[14] * v3.z + sc[15] * v3.w;
        pv_s[wv][d][lane] = a;
    }
    __syncthreads();
    // --- combine: thread handles d = wv*4+dd, n = lane; ao -> kqkv[d][n] ---
    float inv = 1.f / (ps_s[0][lane] + ps_s[1][lane] + ps_s[2][lane] + ps_s[3][lane]);
    #pragma unroll
    for (int dd = 0; dd < 4; ++dd) {
        int d = wv * 4 + dd;
        float o = (pv_s[0][d][lane] + pv_s[1][d][lane]
                 + pv_s[2][d][lane] + pv_s[3][d][lane]) * inv;
        kqkv[d][lane] = o;
    }
    __syncthreads();
    // --- pool over n: 16 partials per d ---
    {
        int d = tid & 15, part = tid >> 4;
        float4 v = *(const float4*)&kqkv[d][part * 4];
        pool2[d][part] = v.x + v.y + v.z + v.w;
    }
    __syncthreads();
    if (tid < 16) {
        float s = 0.f;
        #pragma unroll
        for (int p = 0; p < 16; ++p) s += pool2[tid][p];
        w_mo[b * 64 + h * 16 + tid] = s * (1.f / 64.f);
    }
}

// ---------------------------------------------------------------------------
// 7. Output projection: feat[b][e] = bout[e] + sum_d Wout[e][d] * mo[b][d]
// ---------------------------------------------------------------------------
__global__ void proj_kernel(const float* __restrict__ w_mo,
                            const float* __restrict__ Wout,
                            const float* __restrict__ bout,
                            float* __restrict__ feat) {
    int b = blockIdx.x;
    int tid = threadIdx.x;           // 0..63
    __shared__ float mos[64];
    mos[tid] = w_mo[b * 64 + tid];
    __syncthreads();
    float acc = bout[tid];
    const float4* wr = (const float4*)(Wout + tid * 64);
    #pragma unroll
    for (int d4 = 0; d4 < 16; ++d4) {
        float4 w = wr[d4];
        acc += mos[d4 * 4 + 0] * w.x + mos[d4 * 4 + 1] * w.y
             + mos[d4 * 4 + 2] * w.z + mos[d4 * 4 + 3] * w.w;
    }
    feat[b * NE + tid] = acc;
}

// ---------------------------------------------------------------------------
extern "C" void kernel_launch(void* const* d_in, const int* in_sizes, int n_in,
                              void* d_out, int out_size, void* d_ws, size_t ws_size,
                              hipStream_t stream) {
    const float* eeg      = (const float*)d_in[0];
    const float* gcn1_w   = (const float*)d_in[1];
    const float* gcn1_b   = (const float*)d_in[2];
    const float* gcn2_w   = (const float*)d_in[3];
    const float* gcn2_b   = (const float*)d_in[4];
    const float* bn1_g    = (const float*)d_in[5];
    const float* bn1_b    = (const float*)d_in[6];
    const float* bn2_g    = (const float*)d_in[7];
    const float* bn2_b    = (const float*)d_in[8];
    const float* attn_in_w  = (const float*)d_in[9];
    const float* attn_in_b  = (const float*)d_in[10];
    const float* attn_out_w = (const float*)d_in[11];
    const float* attn_out_b = (const float*)d_in[12];

    float* out  = (float*)d_out;
    float* feat = out;               // [B, E]
    float* wpli = out + NB * NE;     // [B, C, C]

    float* ws = (float*)d_ws;
    float* w_re    = ws;             // [1M] -> reused as s2
    float* w_im    = ws + 1048576;   // [1M]
    float* w_s1    = ws + 2097152;   // [1M]
    float* w_x1    = ws + 3145728;   // [1M]
    float* w_x2    = ws + 4194304;   // [512K]
    float* w_deg   = ws + 4718592;   // [8K]
    float* w_stat1 = ws + 4726784;   // [128]
    float* w_stat2 = ws + 4726912;   // [128]
    float* w_mo    = ws + 4727040;   // [8K]
    float* w_s2    = w_re;

    // 1. analytic signal ([b][c][t] layout)
    analytic_kernel<<<NB * NC, NT, 0, stream>>>(eeg, w_re, w_im);
    // 2. PLI (+deg)
    pli_kernel<<<NB * NC / 4, 256, 0, stream>>>(w_re, w_im, wpli, w_deg);
    // 3. GCN1 support
    gcn_support_v2<NT, false><<<NB * NC / 4, 4 * NT, 0, stream>>>(
        wpli, w_deg, eeg, nullptr, nullptr, nullptr, w_s1);
    // 4. GCN1 linear
    gemm64_kernel<NT, false><<<dim3(NB * NC / 64, HIDN / 64), 256, 0, stream>>>(
        w_s1, gcn1_w, gcn1_b, nullptr, nullptr, nullptr, w_x1, HIDN);
    // 5. BN1 stats
    bn_stats_kernel<<<NC, 1024, 0, stream>>>(w_x1, HIDN, w_stat1);
    // 6. GCN2 support (BN1+ReLU fused at stage)
    gcn_support_v2<HIDN, true><<<NB * NC / 4, 4 * HIDN, 0, stream>>>(
        wpli, w_deg, w_x1, w_stat1, bn1_g, bn1_b, w_s2);
    // 7. GCN2 linear
    gemm64_kernel<HIDN, false><<<dim3(NB * NC / 64, NE / 64), 256, 0, stream>>>(
        w_s2, gcn2_w, gcn2_b, nullptr, nullptr, nullptr, w_x2, NE);
    // 8. BN2 stats
    bn_stats_kernel<<<NC, 1024, 0, stream>>>(w_x2, NE, w_stat2);
    // 9. fused BN2 -> QKV -> attention -> pooled means (per (b,head))
    attn_fused<<<NB * NHD, 256, 0, stream>>>(w_x2, w_stat2, bn2_g, bn2_b,
                                             attn_in_w, attn_in_b, w_mo);
    // 10. output projection
    proj_kernel<<<NB, NE, 0, stream>>>(w_mo, attn_out_w, attn_out_b, feat);
}

// Round 7
// 125.165 us; speedup vs baseline: 1.4024x; 1.1284x over previous
//
#include <hip/hip_runtime.h>
#include <math.h>

#define NB 128     // batch
#define NC 64      // channels
#define NT 128     // segment length
#define HIDN 128   // hidden
#define NE 64      // attn embed
#define NHD 4      // heads
#define HD 16      // head dim

// ---------------------------------------------------------------------------
// 1. Analytic signal (unchanged from round 6; [b][c][t] output).
// ---------------------------------------------------------------------------
__global__ void analytic_kernel(const float* __restrict__ eeg,
                                float* __restrict__ re, float* __restrict__ im) {
    int row = blockIdx.x;            // b*NC + c
    int t = threadIdx.x;             // 0..127
    __shared__ float xs[NT];
    __shared__ double cotv[64];
    xs[t] = eeg[row * NT + t];
    if (t < 64) {
        double d = (double)(2 * t + 1);
        double a = 3.14159265358979323846 * d / 128.0;
        cotv[t] = cos(a) / sin(a);
    }
    __syncthreads();
    double ar = 0.0, ai = 0.0;
    #pragma unroll
    for (int m = 0; m < 64; ++m) {
        int d = 2 * m + 1;
        int s = (t - d) & 127;
        double xv = (double)xs[s];
        ar += xv;
        ai += cotv[m] * xv;
    }
    double rr = (double)xs[t] + ar * (1.0 / 64.0);
    double ii = ai * (1.0 / 64.0);
    re[row * NT + t] = (float)rr;
    im[row * NT + t] = (float)ii;
}

// ---------------------------------------------------------------------------
// 2. PLI v3 (unchanged from round 6). Bit-identical accumulation.
// ---------------------------------------------------------------------------
__global__ void pli_kernel(const float* __restrict__ re, const float* __restrict__ im,
                           float* __restrict__ wpli, float* __restrict__ deg) {
    int b = blockIdx.x >> 4;
    int i0 = (blockIdx.x & 15) << 2;
    int tid = threadIdx.x;           // 256
    int w = tid >> 6;
    int j = tid & 63;
    __shared__ float4 sre4[64 * 32];
    __shared__ float4 sim4[64 * 32];
    __shared__ int pacc[4][4][64];
    const float* reb = re + b * (NC * NT);
    const float* imb = im + b * (NC * NT);
    for (int idx4 = tid; idx4 < 2048; idx4 += 256) {
        int c = idx4 >> 5, t4 = idx4 & 31;
        int slot = c * 32 + (t4 ^ (c & 31));
        sre4[slot] = ((const float4*)reb)[idx4];
        sim4[slot] = ((const float4*)imb)[idx4];
    }
    __syncthreads();
    int acc0 = 0, acc1 = 0, acc2 = 0, acc3 = 0;
    #pragma unroll
    for (int tt = 0; tt < 8; ++tt) {
        int t4 = w * 8 + tt;
        float4 rj = sre4[j * 32 + (t4 ^ (j & 31))];
        float4 ij = sim4[j * 32 + (t4 ^ (j & 31))];
        #pragma unroll
        for (int di = 0; di < 4; ++di) {
            int i = i0 + di;
            float4 ri = sre4[i * 32 + (t4 ^ (i & 31))];
            float4 ii = sim4[i * 32 + (t4 ^ (i & 31))];
            float c0 = ii.x * rj.x - ri.x * ij.x;
            float c1 = ii.y * rj.y - ri.y * ij.y;
            float c2 = ii.z * rj.z - ri.z * ij.z;
            float c3 = ii.w * rj.w - ri.w * ij.w;
            int d = ((c0 > 0.f) ? 1 : ((c0 < 0.f) ? -1 : 0))
                  + ((c1 > 0.f) ? 1 : ((c1 < 0.f) ? -1 : 0))
                  + ((c2 > 0.f) ? 1 : ((c2 < 0.f) ? -1 : 0))
                  + ((c3 > 0.f) ? 1 : ((c3 < 0.f) ? -1 : 0));
            if (di == 0) acc0 += d;
            else if (di == 1) acc1 += d;
            else if (di == 2) acc2 += d;
            else acc3 += d;
        }
    }
    pacc[w][0][j] = acc0; pacc[w][1][j] = acc1;
    pacc[w][2][j] = acc2; pacc[w][3][j] = acc3;
    __syncthreads();
    int di2 = tid >> 6, j2 = tid & 63;
    int a = pacc[0][di2][j2] + pacc[1][di2][j2] + pacc[2][di2][j2] + pacc[3][di2][j2];
    float p = fabsf((float)a * (1.f / (float)NT));
    int i = i0 + di2;
    if (j2 == i) p = 0.f;
    wpli[b * (NC * NC) + i * NC + j2] = p;
    float s = p;
    #pragma unroll
    for (int off = 32; off > 0; off >>= 1) s += __shfl_down(s, off);
    if (j2 == 0) deg[b * NC + i] = s;
}

// ---------------------------------------------------------------------------
// 3. Fused GCN layer: one block per batch, 1024 threads.
//    [optional: reduce BN partials of input + apply BN+ReLU at stage]
//    -> support = A_n @ x in LDS -> x_out = support @ W^T + bias (global)
//    -> per-(b,channel) double partial sums for the NEXT BN (shuffle-16).
// ---------------------------------------------------------------------------
template <int OUT, bool BN_IN>
__global__ __launch_bounds__(1024, 1) void gcn_fused(
        const float* __restrict__ adj, const float* __restrict__ deg,
        const float* __restrict__ x, const double* __restrict__ dpart_in,
        const float* __restrict__ g, const float* __restrict__ bb,
        const float* __restrict__ W, const float* __restrict__ bias,
        float* __restrict__ xout, double* __restrict__ dpart_out) {
    int b = blockIdx.x;
    int tid = threadIdx.x;           // 1024
    __shared__ float dn_s[64];
    __shared__ float stat_s[64][2];
    __shared__ float arow[64][68];   // padded: bank=(4i+j)%32
    __shared__ float xs[64][128];
    __shared__ float sup[64][132];   // padded, 16B-aligned rows
    __shared__ float WsT[128][(OUT == 128) ? 132 : 68];  // [k][o]

    if (tid < 64) {
        dn_s[tid] = (float)(1.0 / sqrt((double)deg[b * 64 + tid] + 1e-8));
    } else if (BN_IN && tid >= 64 && tid < 128) {
        int c = tid - 64;            // reduce BN partials (fixed order, double)
        double s = 0.0, s2 = 0.0;
        for (int bi = 0; bi < NB; ++bi) {
            s  += dpart_in[(bi * 64 + c) * 2];
            s2 += dpart_in[(bi * 64 + c) * 2 + 1];
        }
        double N = (double)(NB * HIDN);
        double m = s / N;
        double var = s2 / N - m * m;
        stat_s[c][0] = (float)m;
        stat_s[c][1] = (float)(1.0 / sqrt(var + 1e-5));
    }
    __syncthreads();
    // stage arow = adj * dn[i] * dn[j]
    {
        int i = tid >> 4, j4 = tid & 15;
        float4 v = *(const float4*)&adj[b * 4096 + i * 64 + j4 * 4];
        float di = dn_s[i];
        v.x = v.x * di * dn_s[j4 * 4 + 0];
        v.y = v.y * di * dn_s[j4 * 4 + 1];
        v.z = v.z * di * dn_s[j4 * 4 + 2];
        v.w = v.w * di * dn_s[j4 * 4 + 3];
        *(float4*)&arow[i][j4 * 4] = v;
    }
    // stage xs (+BN+ReLU for layer 2)
    #pragma unroll
    for (int p = 0; p < 2; ++p) {
        int idx4 = tid + p * 1024;   // 2048 float4
        int r = idx4 >> 5, c4 = idx4 & 31;
        float4 v = ((const float4*)(x + b * 8192))[idx4];
        if (BN_IN) {
            float m = stat_s[r][0], rs = stat_s[r][1], gg = g[r], bv = bb[r];
            v.x = (v.x - m) * rs * gg + bv; v.x = v.x > 0.f ? v.x : 0.f;
            v.y = (v.y - m) * rs * gg + bv; v.y = v.y > 0.f ? v.y : 0.f;
            v.z = (v.z - m) * rs * gg + bv; v.z = v.z > 0.f ? v.z : 0.f;
            v.w = (v.w - m) * rs * gg + bv; v.w = v.w > 0.f ? v.w : 0.f;
        }
        *(float4*)&xs[r][c4 * 4] = v;
    }
    // stage W transposed [k][o]; lanes vary o -> conflict-free LDS writes
    #pragma unroll
    for (int p = 0; p < OUT / 32; ++p) {
        int idx4 = tid + p * 1024;
        int o = idx4 & (OUT - 1);
        int k4 = idx4 / OUT;
        float4 w = *(const float4*)&W[o * 128 + k4 * 4];
        WsT[k4 * 4 + 0][o] = w.x;
        WsT[k4 * 4 + 1][o] = w.y;
        WsT[k4 * 4 + 2][o] = w.z;
        WsT[k4 * 4 + 3][o] = w.w;
    }
    __syncthreads();

    // --- phase 1: support[i][f] = sum_j arow[i][j] * xs[j][f] ---
    int i = tid >> 4;
    {
        int f0 = (tid & 15) * 8;
        float a0 = 0.f, a1 = 0.f, a2 = 0.f, a3 = 0.f,
              a4 = 0.f, a5 = 0.f, a6 = 0.f, a7 = 0.f;
        #pragma unroll 8
        for (int j = 0; j < 64; ++j) {
            float a = arow[i][j];
            float4 x0 = *(const float4*)&xs[j][f0];
            float4 x1v = *(const float4*)&xs[j][f0 + 4];
            a0 += a * x0.x; a1 += a * x0.y; a2 += a * x0.z; a3 += a * x0.w;
            a4 += a * x1v.x; a5 += a * x1v.y; a6 += a * x1v.z; a7 += a * x1v.w;
        }
        *(float4*)&sup[i][f0]     = make_float4(a0, a1, a2, a3);
        *(float4*)&sup[i][f0 + 4] = make_float4(a4, a5, a6, a7);
    }
    __syncthreads();

    // --- phase 2: xout[i][o] = sum_k sup[i][k] * W[o][k] + bias[o] ---
    double ds = 0.0, ds2 = 0.0;
    if (OUT == 128) {
        int o0 = (tid & 15) * 8;
        float c[8] = {};
        #pragma unroll 8
        for (int k = 0; k < 128; ++k) {
            float s = sup[i][k];
            float4 w0 = *(const float4*)&WsT[k][o0];
            float4 w1 = *(const float4*)&WsT[k][o0 + 4];
            c[0] += s * w0.x; c[1] += s * w0.y; c[2] += s * w0.z; c[3] += s * w0.w;
            c[4] += s * w1.x; c[5] += s * w1.y; c[6] += s * w1.z; c[7] += s * w1.w;
        }
        float4 r0 = make_float4(c[0] + bias[o0], c[1] + bias[o0 + 1],
                                c[2] + bias[o0 + 2], c[3] + bias[o0 + 3]);
        float4 r1 = make_float4(c[4] + bias[o0 + 4], c[5] + bias[o0 + 5],
                                c[6] + bias[o0 + 6], c[7] + bias[o0 + 7]);
        *(float4*)&xout[b * 64 * 128 + i * 128 + o0]     = r0;
        *(float4*)&xout[b * 64 * 128 + i * 128 + o0 + 4] = r1;
        ds  = (double)r0.x + (double)r0.y + (double)r0.z + (double)r0.w
            + (double)r1.x + (double)r1.y + (double)r1.z + (double)r1.w;
        ds2 = (double)r0.x * r0.x + (double)r0.y * r0.y + (double)r0.z * r0.z
            + (double)r0.w * r0.w + (double)r1.x * r1.x + (double)r1.y * r1.y
            + (double)r1.z * r1.z + (double)r1.w * r1.w;
    } else {
        int o0 = (tid & 15) * 4;
        float c[4] = {};
        #pragma unroll 8
        for (int k = 0; k < 128; ++k) {
            float s = sup[i][k];
            float4 w0 = *(const float4*)&WsT[k][o0];
            c[0] += s * w0.x; c[1] += s * w0.y; c[2] += s * w0.z; c[3] += s * w0.w;
        }
        float4 r0 = make_float4(c[0] + bias[o0], c[1] + bias[o0 + 1],
                                c[2] + bias[o0 + 2], c[3] + bias[o0 + 3]);
        *(float4*)&xout[b * 64 * 64 + i * 64 + o0] = r0;
        ds  = (double)r0.x + (double)r0.y + (double)r0.z + (double)r0.w;
        ds2 = (double)r0.x * r0.x + (double)r0.y * r0.y + (double)r0.z * r0.z
            + (double)r0.w * r0.w;
    }
    // per-(b, channel=i) partials across the 16 o-octets (lanes tid&15)
    #pragma unroll
    for (int off = 8; off > 0; off >>= 1) {
        ds  += __shfl_down(ds, off, 16);
        ds2 += __shfl_down(ds2, off, 16);
    }
    if ((tid & 15) == 0) {
        dpart_out[(b * 64 + i) * 2]     = ds;
        dpart_out[(b * 64 + i) * 2 + 1] = ds2;
    }
}

// ---------------------------------------------------------------------------
// 4. Attention v5: one block per batch, 1024 threads = 4 heads x 4 j-chunks.
//    Inline BN2-stat reduce, BN2+ReLU, QKV, softmax, PV, pool, out-proj.
// ---------------------------------------------------------------------------
__global__ __launch_bounds__(1024, 1) void attn_fused(
        const float* __restrict__ x2, const double* __restrict__ dpart2,
        const float* __restrict__ g, const float* __restrict__ bb,
        const float* __restrict__ Win, const float* __restrict__ bin,
        const float* __restrict__ Wout, const float* __restrict__ bout,
        float* __restrict__ feat) {
    int b = blockIdx.x;
    int tid = threadIdx.x;
    int lane = tid & 63, wv = tid >> 6;
    int h = wv >> 2, jc = wv & 3;
    __shared__ float stat_s[64][2];
    __shared__ float xs[64][68];     // padded for aligned float4
    __shared__ float ws[192][64];
    __shared__ float kqkv[192][64];  // [o][n]; q rows become ao
    __shared__ float pm_s[4][256], ps_s[4][256];
    __shared__ float pool_s[64][17];
    __shared__ float mo[64];

    if (tid < 64) {                  // BN2 stats (fixed order, double)
        double s = 0.0, s2 = 0.0;
        for (int bi = 0; bi < NB; ++bi) {
            s  += dpart2[(bi * 64 + tid) * 2];
            s2 += dpart2[(bi * 64 + tid) * 2 + 1];
        }
        double N = (double)(NB * NE);
        double m = s / N;
        double var = s2 / N - m * m;
        stat_s[tid][0] = (float)m;
        stat_s[tid][1] = (float)(1.0 / sqrt(var + 1e-5));
    }
    #pragma unroll
    for (int p = 0; p < 3; ++p) {    // stage Win (192x64)
        int idx4 = tid + p * 1024;
        int o = idx4 >> 4, c4 = idx4 & 15;
        *(float4*)&ws[o][c4 * 4] = ((const float4*)(Win + o * 64))[c4];
    }
    __syncthreads();
    {                                // stage x2 with BN2+ReLU
        int r = tid >> 4, c4 = tid & 15;
        float4 v = ((const float4*)(x2 + b * 4096))[tid];
        float m = stat_s[r][0], rs = stat_s[r][1], gg = g[r], bv = bb[r];
        v.x = (v.x - m) * rs * gg + bv; v.x = v.x > 0.f ? v.x : 0.f;
        v.y = (v.y - m) * rs * gg + bv; v.y = v.y > 0.f ? v.y : 0.f;
        v.z = (v.z - m) * rs * gg + bv; v.z = v.z > 0.f ? v.z : 0.f;
        v.w = (v.w - m) * rs * gg + bv; v.w = v.w > 0.f ? v.w : 0.f;
        *(float4*)&xs[r][c4 * 4] = v;
    }
    __syncthreads();

    // --- QKV: thread (n=lane, wv) -> 12 outputs o = wv + 16u ---
    float xr[64];
    #pragma unroll
    for (int d4 = 0; d4 < 16; ++d4) {
        float4 v = *(const float4*)&xs[lane][d4 * 4];
        xr[d4 * 4 + 0] = v.x; xr[d4 * 4 + 1] = v.y;
        xr[d4 * 4 + 2] = v.z; xr[d4 * 4 + 3] = v.w;
    }
    float acc[12];
    #pragma unroll
    for (int u = 0; u < 12; ++u) acc[u] = bin[wv + 16 * u];
    #pragma unroll
    for (int d4 = 0; d4 < 16; ++d4) {
        #pragma unroll
        for (int u = 0; u < 12; ++u) {
            float4 w = *(const float4*)&ws[wv + 16 * u][d4 * 4];  // broadcast
            acc[u] += xr[d4 * 4 + 0] * w.x + xr[d4 * 4 + 1] * w.y
                    + xr[d4 * 4 + 2] * w.z + xr[d4 * 4 + 3] * w.w;
        }
    }
    #pragma unroll
    for (int u = 0; u < 12; ++u) kqkv[wv + 16 * u][lane] = acc[u];
    __syncthreads();

    // --- scores: thread (h, jc, n=lane), 16 keys ---
    int e0 = 16 * h, j0 = jc * 16, hn = h * 64 + lane;
    float q[16];
    #pragma unroll
    for (int d = 0; d < 16; ++d) q[d] = kqkv[e0 + d][lane];
    float sc[16];
    #pragma unroll
    for (int jj = 0; jj < 16; ++jj) sc[jj] = 0.f;
    #pragma unroll
    for (int d = 0; d < 16; ++d) {
        float qd = q[d];
        #pragma unroll
        for (int j4 = 0; j4 < 4; ++j4) {
            float4 kv = *(const float4*)&kqkv[64 + e0 + d][j0 + j4 * 4];  // uniform
            sc[j4 * 4 + 0] += qd * kv.x;
            sc[j4 * 4 + 1] += qd * kv.y;
            sc[j4 * 4 + 2] += qd * kv.z;
            sc[j4 * 4 + 3] += qd * kv.w;
        }
    }
    float pmax = -1e30f;
    #pragma unroll
    for (int jj = 0; jj < 16; ++jj) { sc[jj] *= 0.25f; pmax = fmaxf(pmax, sc[jj]); }
    pm_s[jc][hn] = pmax;
    __syncthreads();
    float mx = fmaxf(fmaxf(pm_s[0][hn], pm_s[1][hn]),
                     fmaxf(pm_s[2][hn], pm_s[3][hn]));
    float psum = 0.f;
    #pragma unroll
    for (int jj = 0; jj < 16; ++jj) { sc[jj] = expf(sc[jj] - mx); psum += sc[jj]; }
    ps_s[jc][hn] = psum;
    float po[16];
    #pragma unroll
    for (int d = 0; d < 16; ++d) {
        float4 v0 = *(const float4*)&kqkv[128 + e0 + d][j0 + 0];
        float4 v1 = *(const float4*)&kqkv[128 + e0 + d][j0 + 4];
        float4 v2 = *(const float4*)&kqkv[128 + e0 + d][j0 + 8];
        float4 v3 = *(const float4*)&kqkv[128 + e0 + d][j0 + 12];
        po[d] = sc[0] * v0.x + sc[1] * v0.y + sc[2] * v0.z + sc[3] * v0.w
              + sc[4] * v1.x + sc[5] * v1.y + sc[6] * v1.z + sc[7] * v1.w
              + sc[8] * v2.x + sc[9] * v2.y + sc[10] * v2.z + sc[11] * v2.w
              + sc[12] * v3.x + sc[13] * v3.y + sc[14] * v3.z + sc[15] * v3.w;
    }
    __syncthreads();
    float inv = 1.f / (ps_s[0][hn] + ps_s[1][hn] + ps_s[2][hn] + ps_s[3][hn]);
    // combine PV partials into dead q rows, deterministic jc order
    if (jc == 0) {
        #pragma unroll
        for (int d = 0; d < 16; ++d) kqkv[e0 + d][lane] = po[d];
    }
    __syncthreads();
    if (jc == 1) {
        #pragma unroll
        for (int d = 0; d < 16; ++d) kqkv[e0 + d][lane] += po[d];
    }
    __syncthreads();
    if (jc == 2) {
        #pragma unroll
        for (int d = 0; d < 16; ++d) kqkv[e0 + d][lane] += po[d];
    }
    __syncthreads();
    if (jc == 3) {
        #pragma unroll
        for (int d = 0; d < 16; ++d)
            kqkv[e0 + d][lane] = (kqkv[e0 + d][lane] + po[d]) * inv;
    }
    __syncthreads();
    // --- pool over n + output projection ---
    {
        int e = tid >> 4, part = tid & 15;
        float4 v = *(const float4*)&kqkv[e][part * 4];
        pool_s[e][part] = v.x + v.y + v.z + v.w;
    }
    __syncthreads();
    if (tid < 64) {
        float s = 0.f;
        #pragma unroll
        for (int p = 0; p < 16; ++p) s += pool_s[tid][p];
        mo[tid] = s * (1.f / 64.f);
    }
    __syncthreads();
    if (tid < 64) {
        float a = bout[tid];
        const float4* wr = (const float4*)(Wout + tid * 64);
        #pragma unroll
        for (int d4 = 0; d4 < 16; ++d4) {
            float4 w = wr[d4];
            a += mo[d4 * 4 + 0] * w.x + mo[d4 * 4 + 1] * w.y
               + mo[d4 * 4 + 2] * w.z + mo[d4 * 4 + 3] * w.w;
        }
        feat[b * NE + tid] = a;
    }
}

// ---------------------------------------------------------------------------
extern "C" void kernel_launch(void* const* d_in, const int* in_sizes, int n_in,
                              void* d_out, int out_size, void* d_ws, size_t ws_size,
                              hipStream_t stream) {
    const float* eeg      = (const float*)d_in[0];
    const float* gcn1_w   = (const float*)d_in[1];
    const float* gcn1_b   = (const float*)d_in[2];
    const float* gcn2_w   = (const float*)d_in[3];
    const float* gcn2_b   = (const float*)d_in[4];
    const float* bn1_g    = (const float*)d_in[5];
    const float* bn1_b    = (const float*)d_in[6];
    const float* bn2_g    = (const float*)d_in[7];
    const float* bn2_b    = (const float*)d_in[8];
    const float* attn_in_w  = (const float*)d_in[9];
    const float* attn_in_b  = (const float*)d_in[10];
    const float* attn_out_w = (const float*)d_in[11];
    const float* attn_out_b = (const float*)d_in[12];

    float* out  = (float*)d_out;
    float* feat = out;               // [B, E]
    float* wpli = out + NB * NE;     // [B, C, C]

    float* ws = (float*)d_ws;
    float*  w_re   = ws;                         // [1M]
    float*  w_im   = ws + 1048576;               // [1M]
    float*  w_x1   = ws + 2097152;               // [1M]
    float*  w_x2   = ws + 3145728;               // [512K]
    float*  w_deg  = ws + 3670016;               // [8K]
    double* dpart1 = (double*)(ws + 3678208);    // [128*64*2 doubles]
    double* dpart2 = (double*)(ws + 3710976);    // [128*64*2 doubles]

    // 1. analytic signal
    analytic_kernel<<<NB * NC, NT, 0, stream>>>(eeg, w_re, w_im);
    // 2. PLI (+deg), writes wpli output
    pli_kernel<<<NB * NC / 4, 256, 0, stream>>>(w_re, w_im, wpli, w_deg);
    // 3. GCN1 fused (support + linear + BN1 partials)
    gcn_fused<HIDN, false><<<NB, 1024, 0, stream>>>(
        wpli, w_deg, eeg, nullptr, nullptr, nullptr,
        gcn1_w, gcn1_b, w_x1, dpart1);
    // 4. GCN2 fused (BN1 reduce+apply + support + linear + BN2 partials)
    gcn_fused<NE, true><<<NB, 1024, 0, stream>>>(
        wpli, w_deg, w_x1, dpart1, bn1_g, bn1_b,
        gcn2_w, gcn2_b, w_x2, dpart2);
    // 5. attention fused (BN2 reduce+apply + QKV + attn + pool + proj)
    attn_fused<<<NB, 1024, 0, stream>>>(w_x2, dpart2, bn2_g, bn2_b,
                                        attn_in_w, attn_in_b,
                                        attn_out_w, attn_out_b, feat);
}